// Round 7
// baseline (585.220 us; speedup 1.0000x reference)
//
#include <hip/hip_runtime.h>
#include <hip/hip_bf16.h>
#include <math.h>

typedef __bf16 bf16;
typedef __bf16 bf16x4 __attribute__((ext_vector_type(4)));
typedef __bf16 bf16x8 __attribute__((ext_vector_type(8)));
typedef float  f32x4  __attribute__((ext_vector_type(4)));

#define DEVI static __device__ __forceinline__

constexpr int B_ = 32, N_ = 4096, DIM_ = 256, NS_ = 11, SP_ = 16, ITERS_ = 3;
constexpr int P_ = 32;                 // attention partitions per batch
constexpr float LN_EPS_ = 1e-3f;
constexpr float EPS_ATTN_ = 1e-8f;

DEVI f32x4 mfma16(bf16x8 a, bf16x8 b, f32x4 c) {
  return __builtin_amdgcn_mfma_f32_16x16x32_bf16(a, b, c, 0, 0, 0);
}

DEVI float wsum64(float v) {
#pragma unroll
  for (int m = 32; m > 0; m >>= 1) v += __shfl_xor(v, m, 64);
  return v;
}

// ---------------- weight cast (fp32 -> bf16), one flat kernel ----------------
__global__ __launch_bounds__(256) void cast_weights(
    const float* __restrict__ Wq, const float* __restrict__ Wk,
    const float* __restrict__ Wv, const float* __restrict__ Wih,
    const float* __restrict__ Whh, const float* __restrict__ W1,
    const float* __restrict__ W2,
    bf16* __restrict__ cWcat, bf16* __restrict__ cWq, bf16* __restrict__ cWih,
    bf16* __restrict__ cWhh, bf16* __restrict__ cW1, bf16* __restrict__ cW2) {
  const int idx = blockIdx.x * 256 + threadIdx.x;
  const int n0 = 512 * 256;            // Wcat = [Wk; Wv] rows
  const int n1 = n0 + 256 * 256;       // Wq
  const int n2 = n1 + 768 * 256;       // Wih
  const int n3 = n2 + 768 * 256;       // Whh
  const int n4 = n3 + 512 * 256;       // W1
  const int n5 = n4 + 256 * 512;       // W2   (total 851968 = 3328*256)
  if (idx < n0) {
    const int r = idx >> 8, c = idx & 255;
    cWcat[idx] = (bf16)((r < 256) ? Wk[r * 256 + c] : Wv[(r - 256) * 256 + c]);
  } else if (idx < n1) { const int i = idx - n0; cWq[i]  = (bf16)Wq[i];
  } else if (idx < n2) { const int i = idx - n1; cWih[i] = (bf16)Wih[i];
  } else if (idx < n3) { const int i = idx - n2; cWhh[i] = (bf16)Whh[i];
  } else if (idx < n4) { const int i = idx - n3; cW1[i]  = (bf16)W1[i];
  } else if (idx < n5) { const int i = idx - n4; cW2[i]  = (bf16)W2[i]; }
}

// ---------------- slot init: mu + exp(log_sigma)*noise ----------------
__global__ __launch_bounds__(256) void init_slots(
    const float* __restrict__ mu, const float* __restrict__ lsig,
    const float* __restrict__ noise, float* __restrict__ slots) {
  const int idx = blockIdx.x * 256 + threadIdx.x;  // B*NS*DIM = 90112 exact
  const int d = idx & 255;
  slots[idx] = mu[d] + expf(lsig[d]) * noise[idx];
}

// ---------------- fused LN(inputs) + K/V projection GEMM ----------------
// grid 2048 (64-row tiles), 256 threads, 48 KiB LDS -> 3 blocks/CU.
// Epilogue: per-wave LDS frag-transpose -> 16B coalesced stores.
// k -> kbuf row-major (B*N,256); v -> vT d-major (B,256,N) via swapped MFMA.
__global__ __launch_bounds__(256) void ln_kv(
    const float* __restrict__ inp, const float* __restrict__ g,
    const float* __restrict__ be, const bf16* __restrict__ Wcat,
    bf16* __restrict__ kbuf, bf16* __restrict__ vT) {
  __shared__ bf16 At[64 * 256];                  // 32 KiB, XOR-swizzled
  __shared__ bf16 scr[4][2048];                  // 16 KiB (4 KiB / wave)
  const int mt = blockIdx.x;
  const int tid = threadIdx.x, lane = tid & 63, wid = tid >> 6;
  const int l15 = lane & 15, gq = lane >> 4;
  // ---- LN phase: 16 lanes/row, 4 rows/iter, 4 iters (16 rows/wave) ----
  float4 gv[4], bv4[4];
#pragma unroll
  for (int u = 0; u < 4; ++u) {
    gv[u]  = ((const float4*)g)[l15 * 4 + u];
    bv4[u] = ((const float4*)be)[l15 * 4 + u];
  }
#pragma unroll
  for (int it4 = 0; it4 < 4; ++it4) {
    const int row = wid * 16 + it4 * 4 + gq;
    const size_t grow = (size_t)mt * 64 + row;
    const float4* rp = (const float4*)(inp + grow * 256 + l15 * 16);
    float4 x[4];
#pragma unroll
    for (int u = 0; u < 4; ++u) x[u] = rp[u];
    float s = 0.f, ss = 0.f;
#pragma unroll
    for (int u = 0; u < 4; ++u) {
      s += x[u].x + x[u].y + x[u].z + x[u].w;
      ss = fmaf(x[u].x, x[u].x, fmaf(x[u].y, x[u].y,
           fmaf(x[u].z, x[u].z, fmaf(x[u].w, x[u].w, ss))));
    }
#pragma unroll
    for (int m = 8; m > 0; m >>= 1) {
      s  += __shfl_xor(s,  m, 16);
      ss += __shfl_xor(ss, m, 16);
    }
    const float mean = s * (1.f / 256.f);
    const float rstd = rsqrtf(ss * (1.f / 256.f) - mean * mean + LN_EPS_);
    bf16x8 y0, y1;
#pragma unroll
    for (int u = 0; u < 2; ++u) {
      y0[u * 4 + 0] = (bf16)((x[u].x - mean) * rstd * gv[u].x + bv4[u].x);
      y0[u * 4 + 1] = (bf16)((x[u].y - mean) * rstd * gv[u].y + bv4[u].y);
      y0[u * 4 + 2] = (bf16)((x[u].z - mean) * rstd * gv[u].z + bv4[u].z);
      y0[u * 4 + 3] = (bf16)((x[u].w - mean) * rstd * gv[u].w + bv4[u].w);
      y1[u * 4 + 0] = (bf16)((x[2+u].x - mean) * rstd * gv[2+u].x + bv4[2+u].x);
      y1[u * 4 + 1] = (bf16)((x[2+u].y - mean) * rstd * gv[2+u].y + bv4[2+u].y);
      y1[u * 4 + 2] = (bf16)((x[2+u].z - mean) * rstd * gv[2+u].z + bv4[2+u].z);
      y1[u * 4 + 3] = (bf16)((x[2+u].w - mean) * rstd * gv[2+u].w + bv4[2+u].w);
    }
    const int base = row * 512 + l15 * 32;
    const int sw = (row & 7) << 4;
    *(bf16x8*)((char*)At + ((base)      ^ sw)) = y0;
    *(bf16x8*)((char*)At + ((base + 16) ^ sw)) = y1;
  }
  __syncthreads();
  // ---- MFMA phase: wave (wr,wc): rows wr*32..+31, cols wc*64 of each cb ----
  const int wr = wid >> 1, wc = wid & 1;
  const int bidx = mt >> 6, jtile = (mt & 63) * 64;
  bf16* sc = scr[wid];
  const int rl = lane >> 3, sc8 = lane & 7;      // K read-phase lane mapping
  // ---------- K half: cb 0,1 (normal orientation, D[j][d]) ----------
  for (int cb = 0; cb < 2; ++cb) {
    f32x4 acc[2][4] = {};
    const bf16* wbase = Wcat + (size_t)(cb * 128 + wc * 64) * 256;
#pragma unroll 2
    for (int kk = 0; kk < 8; ++kk) {
      bf16x8 af[2], bfr[4];
#pragma unroll
      for (int m = 0; m < 2; ++m) {
        const int row = wr * 32 + m * 16 + l15;
        int byte = row * 512 + kk * 64 + gq * 16;
        byte ^= (row & 7) << 4;
        af[m] = *(const bf16x8*)((const char*)At + byte);
      }
#pragma unroll
      for (int n = 0; n < 4; ++n)
        bfr[n] = *(const bf16x8*)(wbase + (size_t)(n * 16 + l15) * 256 + kk * 32 + gq * 8);
#pragma unroll
      for (int m = 0; m < 2; ++m)
#pragma unroll
        for (int n = 0; n < 4; ++n)
          acc[m][n] = mfma16(af[m], bfr[n], acc[m][n]);
    }
    // transpose 32 rows x 64 cols through scr, store 16B-coalesced
#pragma unroll
    for (int m = 0; m < 2; ++m)
#pragma unroll
      for (int n = 0; n < 4; ++n)
#pragma unroll
        for (int r = 0; r < 4; ++r) {
          const int srow = m * 16 + gq * 4 + r;
          const int byte = (srow * 128 + (n * 16 + l15) * 2) ^ ((srow & 7) << 4);
          *(bf16*)((char*)sc + byte) = (bf16)acc[m][n][r];
        }
#pragma unroll
    for (int i = 0; i < 4; ++i) {
      const int srow = i * 8 + rl;
      const int byte = (srow * 128 + sc8 * 16) ^ ((srow & 7) << 4);
      const bf16x8 vv = *(const bf16x8*)((const char*)sc + byte);
      const size_t grow = (size_t)mt * 64 + wr * 32 + srow;
      *(bf16x8*)&kbuf[grow * 256 + cb * 128 + wc * 64 + sc8 * 8] = vv;
    }
  }
  // ---------- V half: cb 2,3 (swapped operands, D[d][j]) ----------
  for (int cbv = 0; cbv < 2; ++cbv) {
    f32x4 acc[4][2] = {};                        // [n = d-block][m = j-block]
    const bf16* wbase = Wcat + (size_t)((2 + cbv) * 128 + wc * 64) * 256;
#pragma unroll 2
    for (int kk = 0; kk < 8; ++kk) {
      bf16x8 af[2], bfr[4];
#pragma unroll
      for (int m = 0; m < 2; ++m) {
        const int row = wr * 32 + m * 16 + l15;
        int byte = row * 512 + kk * 64 + gq * 16;
        byte ^= (row & 7) << 4;
        af[m] = *(const bf16x8*)((const char*)At + byte);
      }
#pragma unroll
      for (int n = 0; n < 4; ++n)
        bfr[n] = *(const bf16x8*)(wbase + (size_t)(n * 16 + l15) * 256 + kk * 32 + gq * 8);
#pragma unroll
      for (int n = 0; n < 4; ++n)
#pragma unroll
        for (int m = 0; m < 2; ++m)
          acc[n][m] = mfma16(bfr[n], af[m], acc[n][m]);
    }
    // transpose 64 d-rows x 32 j-cols through scr (stride 64B rows)
#pragma unroll
    for (int n = 0; n < 4; ++n)
#pragma unroll
      for (int m = 0; m < 2; ++m)
#pragma unroll
        for (int r = 0; r < 4; ++r) {
          const int drow = n * 16 + gq * 4 + r;
          const int byte = (drow * 64 + (m * 16 + l15) * 2) ^ ((drow & 3) << 4);
          *(bf16*)((char*)sc + byte) = (bf16)acc[n][m][r];
        }
    {
      const int rl4 = lane >> 2, sc4 = lane & 3; // 16 d-rows x 4 col-groups
#pragma unroll
      for (int i = 0; i < 4; ++i) {
        const int drow = i * 16 + rl4;
        const int byte = (drow * 64 + sc4 * 16) ^ ((drow & 3) << 4);
        const bf16x8 vv = *(const bf16x8*)((const char*)sc + byte);
        const int dv = cbv * 128 + wc * 64 + drow;
        const int jg = jtile + wr * 32 + sc4 * 8;
        *(bf16x8*)&vT[((size_t)(bidx * 256 + dv)) * N_ + jg] = vv;
      }
    }
  }
}

// ---------------- q projection: LN(slots) @ Wq^T, scaled, bf16, zero-padded ----------------
__global__ __launch_bounds__(256) void q_proj(
    const float* __restrict__ slots, const float* __restrict__ g,
    const float* __restrict__ be, const bf16* __restrict__ Wqb,
    bf16* __restrict__ qpad) {
  const int i = blockIdx.x, b = blockIdx.y, t = threadIdx.x;
  bf16* out = qpad + (b * SP_ + i) * 256;
  if (i >= NS_) { out[t] = (bf16)0.f; return; }   // block-uniform early exit
  __shared__ float lnv[256];
  __shared__ float red[8];
  const float x = slots[(b * NS_ + i) * 256 + t];
  float s = wsum64(x), ss = wsum64(x * x);
  const int lane = t & 63, w = t >> 6;
  if (lane == 0) { red[w] = s; red[4 + w] = ss; }
  __syncthreads();
  const float st = red[0] + red[1] + red[2] + red[3];
  const float qt = red[4] + red[5] + red[6] + red[7];
  const float mean = st / 256.f, var = qt / 256.f - mean * mean;
  const float rstd = rsqrtf(var + LN_EPS_);
  lnv[t] = (x - mean) * rstd * g[t] + be[t];
  __syncthreads();
  float acc = 0.f;
  const bf16* wr = Wqb + (size_t)t * 256;
  for (int it = 0; it < 32; ++it) {
    const bf16x8 wv = *(const bf16x8*)(wr + it * 8);
    const float* u = &lnv[it * 8];
#pragma unroll
    for (int e = 0; e < 8; ++e) acc += (float)wv[e] * u[e];
  }
  out[t] = (bf16)(acc * 0.0625f);                  // fold scale = DIM^-0.5
}

// ---------------- fused attention partial pass ----------------
// grid (P_, B), 256 threads. Each wave: one 32-j chunk.
// Swapped QK^T: D[j][i]; softmax over i (16-lane groups); PV via 16x16x32
// with V fragments loaded contiguously from vT (d-major).
__global__ __launch_bounds__(256) void attn_part(
    const bf16* __restrict__ kbuf, const bf16* __restrict__ vT,
    const bf16* __restrict__ qpad,
    float* __restrict__ num_part, float* __restrict__ den_part) {
  const int part = blockIdx.x, b = blockIdx.y;
  const int lane = threadIdx.x & 63, wid = threadIdx.x >> 6;
  const int l15 = lane & 15, gq = lane >> 4;
  const int jbase = part * 128 + wid * 32;
  const bf16* qrow = qpad + ((size_t)(b * SP_ + l15)) * 256;
  const bf16* kbase = kbuf + ((size_t)(b * N_ + jbase)) * 256;
  const bf16* vtb = vT + ((size_t)b * 256) * N_ + jbase + gq * 8;
  __shared__ float nsw[2][4096];                 // 32 KiB
  __shared__ float dens[4][16];

  float denacc = 0.f;
  float p0[4], p1[4];
#pragma unroll
  for (int T = 0; T < 2; ++T) {
    const bf16* krow = kbase + (size_t)(T * 16 + l15) * 256;
    f32x4 d = {0.f, 0.f, 0.f, 0.f};
#pragma unroll
    for (int kk = 0; kk < 8; ++kk) {
      const bf16x8 ak = *(const bf16x8*)(krow + kk * 32 + gq * 8);
      const bf16x8 bq = *(const bf16x8*)(qrow + kk * 32 + gq * 8);
      d = mfma16(ak, bq, d);
    }
    // softmax over slots i = l15 (across 16-lane groups), per j-row reg
#pragma unroll
    for (int r = 0; r < 4; ++r) {
      float vmax = (l15 < NS_) ? d[r] : -1e30f;
#pragma unroll
      for (int mm = 8; mm > 0; mm >>= 1) vmax = fmaxf(vmax, __shfl_xor(vmax, mm, 16));
      const float e = (l15 < NS_) ? expf(d[r] - vmax) : 0.f;
      float ssum = e;
#pragma unroll
      for (int mm = 8; mm > 0; mm >>= 1) ssum += __shfl_xor(ssum, mm, 16);
      const float p = (l15 < NS_) ? (e / ssum + EPS_ATTN_) : 0.f;
      if (T == 0) p0[r] = p; else p1[r] = p;
      denacc += p;
    }
  }
  // regather P into A-frag layout: ap[e] = P[i=l15][j-local = 8*gq+e]
  bf16x8 ap;
#pragma unroll
  for (int e = 0; e < 8; ++e) {
    const int srcl = l15 + ((2 * (gq & 1) + (e >> 2)) << 4);
    const float v0 = __shfl(p0[e & 3], srcl, 64);
    const float v1 = __shfl(p1[e & 3], srcl, 64);
    ap[e] = (bf16)((gq < 2) ? v0 : v1);
  }
  // PV: num[i][d] += p[i][j] * v[j][d]; B-frag = contiguous 16B from vT
  f32x4 accN[16];
#pragma unroll
  for (int dblk = 0; dblk < 16; ++dblk) {
    const bf16x8 bv = *(const bf16x8*)(vtb + (size_t)(dblk * 16 + l15) * N_);
    f32x4 z = {0.f, 0.f, 0.f, 0.f};
    accN[dblk] = mfma16(ap, bv, z);
  }
  // cross-wave reduce: 2-buffer log tree (2 barriers)
  if (wid < 2) {
#pragma unroll
    for (int dblk = 0; dblk < 16; ++dblk)
#pragma unroll
      for (int r = 0; r < 4; ++r) {
        const int idx = (((4 * gq + r) * 256) + dblk * 16 + l15) ^ (gq << 4);
        nsw[wid][idx] = accN[dblk][r];
      }
  }
  __syncthreads();
  if (wid >= 2) {
#pragma unroll
    for (int dblk = 0; dblk < 16; ++dblk)
#pragma unroll
      for (int r = 0; r < 4; ++r) {
        const int idx = (((4 * gq + r) * 256) + dblk * 16 + l15) ^ (gq << 4);
        nsw[wid - 2][idx] += accN[dblk][r];
      }
  }
  float dtot = denacc + __shfl_xor(denacc, 16, 64);
  dtot += __shfl_xor(dtot, 32, 64);
  if (lane < 16) dens[wid][l15] = dtot;
  __syncthreads();
  const int t = threadIdx.x;
  if (t < NS_)
    den_part[(b * P_ + part) * NS_ + t] =
        dens[0][t] + dens[1][t] + dens[2][t] + dens[3][t];
  for (int r = 0; r < NS_; ++r) {
    const int swz = ((r >> 2) & 3) << 4;
    num_part[((size_t)((b * P_ + part) * NS_ + r)) * 256 + t] =
        nsw[0][(r * 256 + t) ^ swz] + nsw[1][(r * 256 + t) ^ swz];
  }
}

// ---------------- partial reduce + GRU + LN + MLP (512 thr / slot row) ----------------
__global__ __launch_bounds__(512) void gru_mlp(
    const float* __restrict__ num_part, const float* __restrict__ den_part,
    const float* __restrict__ slots_in,
    const bf16* __restrict__ Wih, const bf16* __restrict__ Whh,
    const float* __restrict__ bih, const float* __restrict__ bhh,
    const bf16* __restrict__ W1, const float* __restrict__ b1,
    const bf16* __restrict__ W2, const float* __restrict__ b2,
    const float* __restrict__ gff, const float* __restrict__ beff,
    float* __restrict__ slots_out) {
  const int blk = blockIdx.x, b = blk / NS_, i = blk % NS_;
  const int t = threadIdx.x, tl = t & 255, hi = t >> 8;
  __shared__ float u_s[256], h_s[256], ln_s[256], h1_s[512], gsh[6][256];
  __shared__ float red[8];
  if (hi == 0) {
    float nsum = 0.f;
    for (int p = 0; p < P_; ++p)
      nsum += num_part[((size_t)((b * P_ + p) * NS_ + i)) * 256 + tl];
    float den = 0.f;
    for (int p = 0; p < P_; ++p) den += den_part[(b * P_ + p) * NS_ + i];
    u_s[tl] = nsum / den;
  } else {
    h_s[tl] = slots_in[(b * NS_ + i) * 256 + tl];
  }
  __syncthreads();
  const float* src = hi ? h_s : u_s;
  const bf16* Wb = hi ? Whh : Wih;
  const float* bb = hi ? bhh : bih;
#pragma unroll
  for (int rr = 0; rr < 3; ++rr) {
    const bf16* wrow = Wb + (size_t)(rr * 256 + tl) * 256;
    float a = 0.f;
    for (int it = 0; it < 32; ++it) {
      const bf16x8 wv = *(const bf16x8*)(wrow + it * 8);
#pragma unroll
      for (int e = 0; e < 8; ++e) a += (float)wv[e] * src[it * 8 + e];
    }
    gsh[hi * 3 + rr][tl] = a + bb[rr * 256 + tl];
  }
  __syncthreads();
  float hn = 0.f;
  if (hi == 0) {
    const float r = 1.f / (1.f + expf(-(gsh[0][tl] + gsh[3][tl])));
    const float z = 1.f / (1.f + expf(-(gsh[1][tl] + gsh[4][tl])));
    const float n = tanhf(gsh[2][tl] + r * gsh[5][tl]);
    hn = (1.f - z) * n + z * h_s[tl];
    float s = wsum64(hn), ss = wsum64(hn * hn);
    if ((t & 63) == 0) { red[t >> 6] = s; red[4 + (t >> 6)] = ss; }
  }
  __syncthreads();
  if (hi == 0) {
    const float st = red[0] + red[1] + red[2] + red[3];
    const float qt = red[4] + red[5] + red[6] + red[7];
    const float mean = st / 256.f, var = qt / 256.f - mean * mean;
    const float rstd = rsqrtf(var + LN_EPS_);
    ln_s[tl] = (hn - mean) * rstd * gff[tl] + beff[tl];
  }
  __syncthreads();
  {  // W1: all 512 threads, one hidden row each
    const bf16* w1r = W1 + (size_t)t * 256;
    float acc = 0.f;
    for (int it = 0; it < 32; ++it) {
      const bf16x8 wv = *(const bf16x8*)(w1r + it * 8);
#pragma unroll
      for (int e2 = 0; e2 < 8; ++e2) acc += (float)wv[e2] * ln_s[it * 8 + e2];
    }
    h1_s[t] = fmaxf(acc + b1[t], 0.f);
  }
  __syncthreads();
  if (hi == 0) {
    const bf16* w2r = W2 + (size_t)tl * 512;
    float acc = 0.f;
    for (int it = 0; it < 64; ++it) {
      const bf16x8 wv = *(const bf16x8*)(w2r + it * 8);
#pragma unroll
      for (int e2 = 0; e2 < 8; ++e2) acc += (float)wv[e2] * h1_s[it * 8 + e2];
    }
    slots_out[(b * NS_ + i) * 256 + tl] = hn + acc + b2[tl];
  }
}

// ---------------- launcher ----------------
extern "C" void kernel_launch(void* const* d_in, const int* in_sizes, int n_in,
                              void* d_out, int out_size, void* d_ws, size_t ws_size,
                              hipStream_t stream) {
  const float* inputs = (const float*)d_in[0];
  const float* noise  = (const float*)d_in[1];
  const float* mu     = (const float*)d_in[2];
  const float* lsig   = (const float*)d_in[3];
  const float* Wq     = (const float*)d_in[4];
  const float* Wk     = (const float*)d_in[5];
  const float* Wv     = (const float*)d_in[6];
  const float* Wih    = (const float*)d_in[7];
  const float* Whh    = (const float*)d_in[8];
  const float* bih    = (const float*)d_in[9];
  const float* bhh    = (const float*)d_in[10];
  const float* W1     = (const float*)d_in[11];
  const float* b1     = (const float*)d_in[12];
  const float* W2     = (const float*)d_in[13];
  const float* b2     = (const float*)d_in[14];
  const float* gin    = (const float*)d_in[15];
  const float* bein   = (const float*)d_in[16];
  const float* gsl    = (const float*)d_in[17];
  const float* besl   = (const float*)d_in[18];
  const float* gff    = (const float*)d_in[19];
  const float* beff   = (const float*)d_in[20];

  char* ws = (char*)d_ws;
  size_t off = 0;
  auto alloc = [&](size_t bytes) -> void* {
    void* p = ws + off;
    off += (bytes + 255) & ~(size_t)255;
    return p;
  };
  bf16*  kbuf    = (bf16*) alloc((size_t)B_ * N_ * 256 * 2);    // 64 MiB
  bf16*  vT      = (bf16*) alloc((size_t)B_ * 256 * N_ * 2);    // 64 MiB
  bf16*  qpad    = (bf16*) alloc((size_t)B_ * SP_ * 256 * 2);
  bf16*  cWcat   = (bf16*) alloc(512 * 256 * 2);
  bf16*  cWq     = (bf16*) alloc(256 * 256 * 2);
  bf16*  cWih    = (bf16*) alloc(768 * 256 * 2);
  bf16*  cWhh    = (bf16*) alloc(768 * 256 * 2);
  bf16*  cW1     = (bf16*) alloc(512 * 256 * 2);
  bf16*  cW2     = (bf16*) alloc(256 * 512 * 2);
  float* slots   = (float*)alloc((size_t)B_ * NS_ * 256 * 4);
  float* numpart = (float*)alloc((size_t)B_ * P_ * NS_ * 256 * 4); // 11.5 MB
  float* denpart = (float*)alloc((size_t)B_ * P_ * NS_ * 4);
  (void)ws_size; (void)in_sizes; (void)n_in; (void)out_size;

  cast_weights<<<3328, 256, 0, stream>>>(Wq, Wk, Wv, Wih, Whh, W1, W2,
                                         cWcat, cWq, cWih, cWhh, cW1, cW2);
  init_slots<<<352, 256, 0, stream>>>(mu, lsig, noise, slots);
  ln_kv<<<2048, 256, 0, stream>>>(inputs, gin, bein, cWcat, kbuf, vT);
  for (int it = 0; it < ITERS_; ++it) {
    q_proj<<<dim3(SP_, B_), 256, 0, stream>>>(slots, gsl, besl, cWq, qpad);
    attn_part<<<dim3(P_, B_), 256, 0, stream>>>(kbuf, vT, qpad, numpart, denpart);
    float* sout = (it == ITERS_ - 1) ? (float*)d_out : slots;
    gru_mlp<<<B_ * NS_, 512, 0, stream>>>(numpart, denpart, slots,
        cWih, cWhh, bih, bhh, cW1, b1, cW2, b2, gff, beff, sout);
  }
}

// Round 9
// 548.838 us; speedup vs baseline: 1.0663x; 1.0663x over previous
//
#include <hip/hip_runtime.h>
#include <hip/hip_bf16.h>
#include <math.h>

typedef __bf16 bf16;
typedef __bf16 bf16x4 __attribute__((ext_vector_type(4)));
typedef __bf16 bf16x8 __attribute__((ext_vector_type(8)));
typedef float  f32x4  __attribute__((ext_vector_type(4)));

#define DEVI static __device__ __forceinline__

constexpr int B_ = 32, N_ = 4096, DIM_ = 256, NS_ = 11, SP_ = 16, ITERS_ = 3;
constexpr int P_ = 32;                 // attention partitions per batch
constexpr float LN_EPS_ = 1e-3f;
constexpr float EPS_ATTN_ = 1e-8f;

DEVI f32x4 mfma16(bf16x8 a, bf16x8 b, f32x4 c) {
  return __builtin_amdgcn_mfma_f32_16x16x32_bf16(a, b, c, 0, 0, 0);
}

DEVI float wsum64(float v) {
#pragma unroll
  for (int m = 32; m > 0; m >>= 1) v += __shfl_xor(v, m, 64);
  return v;
}

// ---------------- weight cast (fp32 -> bf16), one flat kernel ----------------
__global__ __launch_bounds__(256) void cast_weights(
    const float* __restrict__ Wq, const float* __restrict__ Wk,
    const float* __restrict__ Wv, const float* __restrict__ Wih,
    const float* __restrict__ Whh, const float* __restrict__ W1,
    const float* __restrict__ W2,
    bf16* __restrict__ cWcat, bf16* __restrict__ cWq, bf16* __restrict__ cWih,
    bf16* __restrict__ cWhh, bf16* __restrict__ cW1, bf16* __restrict__ cW2) {
  const int idx = blockIdx.x * 256 + threadIdx.x;
  const int n0 = 512 * 256;            // Wcat = [Wk; Wv] rows
  const int n1 = n0 + 256 * 256;       // Wq
  const int n2 = n1 + 768 * 256;       // Wih
  const int n3 = n2 + 768 * 256;       // Whh
  const int n4 = n3 + 512 * 256;       // W1
  const int n5 = n4 + 256 * 512;       // W2   (total 851968 = 3328*256)
  if (idx < n0) {
    const int r = idx >> 8, c = idx & 255;
    cWcat[idx] = (bf16)((r < 256) ? Wk[r * 256 + c] : Wv[(r - 256) * 256 + c]);
  } else if (idx < n1) { const int i = idx - n0; cWq[i]  = (bf16)Wq[i];
  } else if (idx < n2) { const int i = idx - n1; cWih[i] = (bf16)Wih[i];
  } else if (idx < n3) { const int i = idx - n2; cWhh[i] = (bf16)Whh[i];
  } else if (idx < n4) { const int i = idx - n3; cW1[i]  = (bf16)W1[i];
  } else if (idx < n5) { const int i = idx - n4; cW2[i]  = (bf16)W2[i]; }
}

// ---------------- slot init: mu + exp(log_sigma)*noise ----------------
__global__ __launch_bounds__(256) void init_slots(
    const float* __restrict__ mu, const float* __restrict__ lsig,
    const float* __restrict__ noise, float* __restrict__ slots) {
  const int idx = blockIdx.x * 256 + threadIdx.x;  // B*NS*DIM = 90112 exact
  const int d = idx & 255;
  slots[idx] = mu[d] + expf(lsig[d]) * noise[idx];
}

// ---------------- fused LN(inputs) + K/V projection GEMM ----------------
// grid 1024 (128-row tiles), 256 threads (R3 structure, best measured).
// k -> kbuf row-major (B*N,256) normal MFMA; v -> vT d-major (B,256,N)
// via SWAPPED-operand MFMA (stores land as 32B runs).
__global__ __launch_bounds__(256) void ln_kv(
    const float* __restrict__ inp, const float* __restrict__ g,
    const float* __restrict__ be, const bf16* __restrict__ Wcat,
    bf16* __restrict__ kbuf, bf16* __restrict__ vT) {
  __shared__ bf16 At[128 * 256];                     // 64 KiB, XOR-swizzled
  const int mt = blockIdx.x;
  const int tid = threadIdx.x, lane = tid & 63, wid = tid >> 6;
  const int l15 = lane & 15, gq = lane >> 4;
  // LN phase: 16 lanes per row, 4 rows per wave-iter, 8 iters
  float4 gv[4], bv4[4];
#pragma unroll
  for (int u = 0; u < 4; ++u) {
    gv[u]  = ((const float4*)g)[l15 * 4 + u];
    bv4[u] = ((const float4*)be)[l15 * 4 + u];
  }
  for (int it8 = 0; it8 < 8; ++it8) {
    const int row = wid * 32 + it8 * 4 + gq;
    const size_t grow = (size_t)mt * 128 + row;
    const float4* rp = (const float4*)(inp + grow * 256 + l15 * 16);
    float4 x[4];
#pragma unroll
    for (int u = 0; u < 4; ++u) x[u] = rp[u];
    float s = 0.f, ss = 0.f;
#pragma unroll
    for (int u = 0; u < 4; ++u) {
      s += x[u].x + x[u].y + x[u].z + x[u].w;
      ss = fmaf(x[u].x, x[u].x, fmaf(x[u].y, x[u].y,
           fmaf(x[u].z, x[u].z, fmaf(x[u].w, x[u].w, ss))));
    }
#pragma unroll
    for (int m = 8; m > 0; m >>= 1) {
      s  += __shfl_xor(s,  m, 16);
      ss += __shfl_xor(ss, m, 16);
    }
    const float mean = s * (1.f / 256.f);
    const float rstd = rsqrtf(ss * (1.f / 256.f) - mean * mean + LN_EPS_);
    bf16x8 y0, y1;
#pragma unroll
    for (int u = 0; u < 2; ++u) {
      y0[u * 4 + 0] = (bf16)((x[u].x - mean) * rstd * gv[u].x + bv4[u].x);
      y0[u * 4 + 1] = (bf16)((x[u].y - mean) * rstd * gv[u].y + bv4[u].y);
      y0[u * 4 + 2] = (bf16)((x[u].z - mean) * rstd * gv[u].z + bv4[u].z);
      y0[u * 4 + 3] = (bf16)((x[u].w - mean) * rstd * gv[u].w + bv4[u].w);
      y1[u * 4 + 0] = (bf16)((x[2+u].x - mean) * rstd * gv[2+u].x + bv4[2+u].x);
      y1[u * 4 + 1] = (bf16)((x[2+u].y - mean) * rstd * gv[2+u].y + bv4[2+u].y);
      y1[u * 4 + 2] = (bf16)((x[2+u].z - mean) * rstd * gv[2+u].z + bv4[2+u].z);
      y1[u * 4 + 3] = (bf16)((x[2+u].w - mean) * rstd * gv[2+u].w + bv4[2+u].w);
    }
    const int base = row * 512 + l15 * 32;
    const int sw = (row & 7) << 4;
    *(bf16x8*)((char*)At + ((base)      ^ sw)) = y0;
    *(bf16x8*)((char*)At + ((base + 16) ^ sw)) = y1;
  }
  __syncthreads();
  // MFMA phase: wave (wr,wc) owns 64x64 of each 128-col block
  const int wr = wid >> 1, wc = wid & 1;
  const int bidx = mt >> 5, jtile = (mt & 31) * 128;
  // ---------- K half: cb 0,1 (normal orientation, D[j][d]) ----------
  for (int cb = 0; cb < 2; ++cb) {
    f32x4 acc[4][4] = {};
    const bf16* wbase = Wcat + (size_t)(cb * 128 + wc * 64) * 256;
    for (int kk = 0; kk < 8; ++kk) {
      bf16x8 af[4], bfr[4];
#pragma unroll
      for (int m = 0; m < 4; ++m) {
        const int row = wr * 64 + m * 16 + l15;
        int byte = row * 512 + kk * 64 + gq * 16;
        byte ^= (row & 7) << 4;
        af[m] = *(const bf16x8*)((const char*)At + byte);
      }
#pragma unroll
      for (int n = 0; n < 4; ++n)
        bfr[n] = *(const bf16x8*)(wbase + (size_t)(n * 16 + l15) * 256 + kk * 32 + gq * 8);
#pragma unroll
      for (int m = 0; m < 4; ++m)
#pragma unroll
        for (int n = 0; n < 4; ++n)
          acc[m][n] = mfma16(af[m], bfr[n], acc[m][n]);
    }
#pragma unroll
    for (int m = 0; m < 4; ++m)
#pragma unroll
      for (int n = 0; n < 4; ++n)
#pragma unroll
        for (int r = 0; r < 4; ++r) {
          const size_t grow = (size_t)mt * 128 + wr * 64 + m * 16 + gq * 4 + r;
          const int col = cb * 128 + wc * 64 + n * 16 + l15;
          kbuf[grow * 256 + col] = (bf16)acc[m][n][r];
        }
  }
  // ---------- V half: cb 2,3 (SWAPPED operands, D[d][j]) ----------
  for (int cbv = 0; cbv < 2; ++cbv) {
    f32x4 acc[4][4] = {};                        // [n = d-block][m = j-block]
    const bf16* wbase = Wcat + (size_t)((2 + cbv) * 128 + wc * 64) * 256;
    for (int kk = 0; kk < 8; ++kk) {
      bf16x8 af[4], bfr[4];
#pragma unroll
      for (int m = 0; m < 4; ++m) {
        const int row = wr * 64 + m * 16 + l15;
        int byte = row * 512 + kk * 64 + gq * 16;
        byte ^= (row & 7) << 4;
        af[m] = *(const bf16x8*)((const char*)At + byte);
      }
#pragma unroll
      for (int n = 0; n < 4; ++n)
        bfr[n] = *(const bf16x8*)(wbase + (size_t)(n * 16 + l15) * 256 + kk * 32 + gq * 8);
#pragma unroll
      for (int n = 0; n < 4; ++n)
#pragma unroll
        for (int m = 0; m < 4; ++m)
          acc[n][m] = mfma16(bfr[n], af[m], acc[n][m]);
    }
#pragma unroll
    for (int n = 0; n < 4; ++n)
#pragma unroll
      for (int m = 0; m < 4; ++m)
#pragma unroll
        for (int r = 0; r < 4; ++r) {
          const int d = cbv * 128 + wc * 64 + n * 16 + gq * 4 + r;
          const int j = jtile + wr * 64 + m * 16 + l15;
          vT[((size_t)(bidx * 256 + d)) * N_ + j] = (bf16)acc[n][m][r];
        }
  }
}

// ---------------- q projection: LN(slots) @ Wq^T, scaled, bf16, zero-padded ----------------
__global__ __launch_bounds__(256) void q_proj(
    const float* __restrict__ slots, const float* __restrict__ g,
    const float* __restrict__ be, const bf16* __restrict__ Wqb,
    bf16* __restrict__ qpad) {
  const int i = blockIdx.x, b = blockIdx.y, t = threadIdx.x;
  bf16* out = qpad + (b * SP_ + i) * 256;
  if (i >= NS_) { out[t] = (bf16)0.f; return; }   // block-uniform early exit
  __shared__ float lnv[256];
  __shared__ float red[8];
  const float x = slots[(b * NS_ + i) * 256 + t];
  float s = wsum64(x), ss = wsum64(x * x);
  const int lane = t & 63, w = t >> 6;
  if (lane == 0) { red[w] = s; red[4 + w] = ss; }
  __syncthreads();
  const float st = red[0] + red[1] + red[2] + red[3];
  const float qt = red[4] + red[5] + red[6] + red[7];
  const float mean = st / 256.f, var = qt / 256.f - mean * mean;
  const float rstd = rsqrtf(var + LN_EPS_);
  lnv[t] = (x - mean) * rstd * g[t] + be[t];
  __syncthreads();
  float acc = 0.f;
  const bf16* wr = Wqb + (size_t)t * 256;
  for (int it = 0; it < 32; ++it) {
    const bf16x8 wv = *(const bf16x8*)(wr + it * 8);
    const float* u = &lnv[it * 8];
#pragma unroll
    for (int e = 0; e < 8; ++e) acc += (float)wv[e] * u[e];
  }
  out[t] = (bf16)(acc * 0.0625f);                  // fold scale = DIM^-0.5
}

// ---------------- fused attention partial pass ----------------
// grid (P_, B), 256 threads. Each wave: one 32-j chunk.
// Latency-restructured: q-frags hoisted; V prefetched in halves so HBM/L2
// latency hides under QK^T + softmax + regather; setprio around PV MFMAs.
__global__ __launch_bounds__(256) void attn_part(
    const bf16* __restrict__ kbuf, const bf16* __restrict__ vT,
    const bf16* __restrict__ qpad,
    float* __restrict__ num_part, float* __restrict__ den_part) {
  const int part = blockIdx.x, b = blockIdx.y;
  const int lane = threadIdx.x & 63, wid = threadIdx.x >> 6;
  const int l15 = lane & 15, gq = lane >> 4;
  const int jbase = part * 128 + wid * 32;
  const bf16* qrow = qpad + ((size_t)(b * SP_ + l15)) * 256;
  const bf16* kbase = kbuf + ((size_t)(b * N_ + jbase)) * 256;
  const bf16* vtb = vT + ((size_t)b * 256) * N_ + jbase + gq * 8;
  __shared__ float nsw[2][4096];                 // 32 KiB
  __shared__ float dens[4][16];

  // hoisted q fragments (identical for both T halves)
  bf16x8 bq[8];
#pragma unroll
  for (int kk = 0; kk < 8; ++kk)
    bq[kk] = *(const bf16x8*)(qrow + kk * 32 + gq * 8);
  // prefetch V lower half (d 0..127) — consumed after softmax
  bf16x8 v0[8];
#pragma unroll
  for (int dblk = 0; dblk < 8; ++dblk)
    v0[dblk] = *(const bf16x8*)(vtb + (size_t)(dblk * 16 + l15) * N_);

  float denacc = 0.f;
  float p0[4], p1[4];
#pragma unroll
  for (int T = 0; T < 2; ++T) {
    const bf16* krow = kbase + (size_t)(T * 16 + l15) * 256;
    f32x4 d = {0.f, 0.f, 0.f, 0.f};
#pragma unroll
    for (int kk = 0; kk < 8; ++kk) {
      const bf16x8 ak = *(const bf16x8*)(krow + kk * 32 + gq * 8);
      d = mfma16(ak, bq[kk], d);
    }
    // softmax over slots i = l15 (across 16-lane groups), per j-row reg
#pragma unroll
    for (int r = 0; r < 4; ++r) {
      float vmax = (l15 < NS_) ? d[r] : -1e30f;
#pragma unroll
      for (int mm = 8; mm > 0; mm >>= 1) vmax = fmaxf(vmax, __shfl_xor(vmax, mm, 16));
      const float e = (l15 < NS_) ? expf(d[r] - vmax) : 0.f;
      float ssum = e;
#pragma unroll
      for (int mm = 8; mm > 0; mm >>= 1) ssum += __shfl_xor(ssum, mm, 16);
      const float p = (l15 < NS_) ? (e / ssum + EPS_ATTN_) : 0.f;
      if (T == 0) p0[r] = p; else p1[r] = p;
      denacc += p;
    }
  }
  // prefetch V upper half (d 128..255) — consumed after regather + PV0
  bf16x8 v1[8];
#pragma unroll
  for (int dblk = 0; dblk < 8; ++dblk)
    v1[dblk] = *(const bf16x8*)(vtb + (size_t)((8 + dblk) * 16 + l15) * N_);
  // regather P into A-frag layout: ap[e] = P[i=l15][j-local = 8*gq+e]
  bf16x8 ap;
#pragma unroll
  for (int e = 0; e < 8; ++e) {
    const int srcl = l15 + ((2 * (gq & 1) + (e >> 2)) << 4);
    const float va = __shfl(p0[e & 3], srcl, 64);
    const float vb = __shfl(p1[e & 3], srcl, 64);
    ap[e] = (bf16)((gq < 2) ? va : vb);
  }
  // PV: num[i][d] += p[i][j] * v[j][d]
  f32x4 accN[16];
  __builtin_amdgcn_s_setprio(1);
#pragma unroll
  for (int dblk = 0; dblk < 8; ++dblk) {
    f32x4 z = {0.f, 0.f, 0.f, 0.f};
    accN[dblk] = mfma16(ap, v0[dblk], z);
  }
#pragma unroll
  for (int dblk = 0; dblk < 8; ++dblk) {
    f32x4 z = {0.f, 0.f, 0.f, 0.f};
    accN[8 + dblk] = mfma16(ap, v1[dblk], z);
  }
  __builtin_amdgcn_s_setprio(0);
  // cross-wave reduce: 2-buffer log tree (2 barriers)
  if (wid < 2) {
#pragma unroll
    for (int dblk = 0; dblk < 16; ++dblk)
#pragma unroll
      for (int r = 0; r < 4; ++r) {
        const int idx = (((4 * gq + r) * 256) + dblk * 16 + l15) ^ (gq << 4);
        nsw[wid][idx] = accN[dblk][r];
      }
  }
  __syncthreads();
  if (wid >= 2) {
#pragma unroll
    for (int dblk = 0; dblk < 16; ++dblk)
#pragma unroll
      for (int r = 0; r < 4; ++r) {
        const int idx = (((4 * gq + r) * 256) + dblk * 16 + l15) ^ (gq << 4);
        nsw[wid - 2][idx] += accN[dblk][r];
      }
  }
  float dtot = denacc + __shfl_xor(denacc, 16, 64);
  dtot += __shfl_xor(dtot, 32, 64);
  if (lane < 16) dens[wid][l15] = dtot;
  __syncthreads();
  const int t = threadIdx.x;
  if (t < NS_)
    den_part[(b * P_ + part) * NS_ + t] =
        dens[0][t] + dens[1][t] + dens[2][t] + dens[3][t];
  for (int r = 0; r < NS_; ++r) {
    const int swz = ((r >> 2) & 3) << 4;
    num_part[((size_t)((b * P_ + part) * NS_ + r)) * 256 + t] =
        nsw[0][(r * 256 + t) ^ swz] + nsw[1][(r * 256 + t) ^ swz];
  }
}

// ---------------- partial reduce + GRU + LN + MLP (512 thr / slot row) ----------------
__global__ __launch_bounds__(512) void gru_mlp(
    const float* __restrict__ num_part, const float* __restrict__ den_part,
    const float* __restrict__ slots_in,
    const bf16* __restrict__ Wih, const bf16* __restrict__ Whh,
    const float* __restrict__ bih, const float* __restrict__ bhh,
    const bf16* __restrict__ W1, const float* __restrict__ b1,
    const bf16* __restrict__ W2, const float* __restrict__ b2,
    const float* __restrict__ gff, const float* __restrict__ beff,
    float* __restrict__ slots_out) {
  const int blk = blockIdx.x, b = blk / NS_, i = blk % NS_;
  const int t = threadIdx.x, tl = t & 255, hi = t >> 8;
  __shared__ float u_s[256], h_s[256], ln_s[256], h1_s[512], gsh[6][256];
  __shared__ float red[8];
  if (hi == 0) {
    float nsum = 0.f;
    for (int p = 0; p < P_; ++p)
      nsum += num_part[((size_t)((b * P_ + p) * NS_ + i)) * 256 + tl];
    float den = 0.f;
    for (int p = 0; p < P_; ++p) den += den_part[(b * P_ + p) * NS_ + i];
    u_s[tl] = nsum / den;
  } else {
    h_s[tl] = slots_in[(b * NS_ + i) * 256 + tl];
  }
  __syncthreads();
  const float* src = hi ? h_s : u_s;
  const bf16* Wb = hi ? Whh : Wih;
  const float* bb = hi ? bhh : bih;
#pragma unroll
  for (int rr = 0; rr < 3; ++rr) {
    const bf16* wrow = Wb + (size_t)(rr * 256 + tl) * 256;
    float a = 0.f;
    for (int it = 0; it < 32; ++it) {
      const bf16x8 wv = *(const bf16x8*)(wrow + it * 8);
#pragma unroll
      for (int e = 0; e < 8; ++e) a += (float)wv[e] * src[it * 8 + e];
    }
    gsh[hi * 3 + rr][tl] = a + bb[rr * 256 + tl];
  }
  __syncthreads();
  float hn = 0.f;
  if (hi == 0) {
    const float r = 1.f / (1.f + expf(-(gsh[0][tl] + gsh[3][tl])));
    const float z = 1.f / (1.f + expf(-(gsh[1][tl] + gsh[4][tl])));
    const float n = tanhf(gsh[2][tl] + r * gsh[5][tl]);
    hn = (1.f - z) * n + z * h_s[tl];
    float s = wsum64(hn), ss = wsum64(hn * hn);
    if ((t & 63) == 0) { red[t >> 6] = s; red[4 + (t >> 6)] = ss; }
  }
  __syncthreads();
  if (hi == 0) {
    const float st = red[0] + red[1] + red[2] + red[3];
    const float qt = red[4] + red[5] + red[6] + red[7];
    const float mean = st / 256.f, var = qt / 256.f - mean * mean;
    const float rstd = rsqrtf(var + LN_EPS_);
    ln_s[tl] = (hn - mean) * rstd * gff[tl] + beff[tl];
  }
  __syncthreads();
  {  // W1: all 512 threads, one hidden row each
    const bf16* w1r = W1 + (size_t)t * 256;
    float acc = 0.f;
    for (int it = 0; it < 32; ++it) {
      const bf16x8 wv = *(const bf16x8*)(w1r + it * 8);
#pragma unroll
      for (int e2 = 0; e2 < 8; ++e2) acc += (float)wv[e2] * ln_s[it * 8 + e2];
    }
    h1_s[t] = fmaxf(acc + b1[t], 0.f);
  }
  __syncthreads();
  if (hi == 0) {
    const bf16* w2r = W2 + (size_t)tl * 512;
    float acc = 0.f;
    for (int it = 0; it < 64; ++it) {
      const bf16x8 wv = *(const bf16x8*)(w2r + it * 8);
#pragma unroll
      for (int e2 = 0; e2 < 8; ++e2) acc += (float)wv[e2] * h1_s[it * 8 + e2];
    }
    slots_out[(b * NS_ + i) * 256 + tl] = hn + acc + b2[tl];
  }
}

// ---------------- launcher ----------------
extern "C" void kernel_launch(void* const* d_in, const int* in_sizes, int n_in,
                              void* d_out, int out_size, void* d_ws, size_t ws_size,
                              hipStream_t stream) {
  const float* inputs = (const float*)d_in[0];
  const float* noise  = (const float*)d_in[1];
  const float* mu     = (const float*)d_in[2];
  const float* lsig   = (const float*)d_in[3];
  const float* Wq     = (const float*)d_in[4];
  const float* Wk     = (const float*)d_in[5];
  const float* Wv     = (const float*)d_in[6];
  const float* Wih    = (const float*)d_in[7];
  const float* Whh    = (const float*)d_in[8];
  const float* bih    = (const float*)d_in[9];
  const float* bhh    = (const float*)d_in[10];
  const float* W1     = (const float*)d_in[11];
  const float* b1     = (const float*)d_in[12];
  const float* W2     = (const float*)d_in[13];
  const float* b2     = (const float*)d_in[14];
  const float* gin    = (const float*)d_in[15];
  const float* bein   = (const float*)d_in[16];
  const float* gsl    = (const float*)d_in[17];
  const float* besl   = (const float*)d_in[18];
  const float* gff    = (const float*)d_in[19];
  const float* beff   = (const float*)d_in[20];

  char* ws = (char*)d_ws;
  size_t off = 0;
  auto alloc = [&](size_t bytes) -> void* {
    void* p = ws + off;
    off += (bytes + 255) & ~(size_t)255;
    return p;
  };
  bf16*  kbuf    = (bf16*) alloc((size_t)B_ * N_ * 256 * 2);    // 64 MiB
  bf16*  vT      = (bf16*) alloc((size_t)B_ * 256 * N_ * 2);    // 64 MiB
  bf16*  qpad    = (bf16*) alloc((size_t)B_ * SP_ * 256 * 2);
  bf16*  cWcat   = (bf16*) alloc(512 * 256 * 2);
  bf16*  cWq     = (bf16*) alloc(256 * 256 * 2);
  bf16*  cWih    = (bf16*) alloc(768 * 256 * 2);
  bf16*  cWhh    = (bf16*) alloc(768 * 256 * 2);
  bf16*  cW1     = (bf16*) alloc(512 * 256 * 2);
  bf16*  cW2     = (bf16*) alloc(256 * 512 * 2);
  float* slots   = (float*)alloc((size_t)B_ * NS_ * 256 * 4);
  float* numpart = (float*)alloc((size_t)B_ * P_ * NS_ * 256 * 4); // 11.5 MB
  float* denpart = (float*)alloc((size_t)B_ * P_ * NS_ * 4);
  (void)ws_size; (void)in_sizes; (void)n_in; (void)out_size;

  cast_weights<<<3328, 256, 0, stream>>>(Wq, Wk, Wv, Wih, Whh, W1, W2,
                                         cWcat, cWq, cWih, cWhh, cW1, cW2);
  init_slots<<<352, 256, 0, stream>>>(mu, lsig, noise, slots);
  ln_kv<<<1024, 256, 0, stream>>>(inputs, gin, bein, cWcat, kbuf, vT);
  for (int it = 0; it < ITERS_; ++it) {
    q_proj<<<dim3(SP_, B_), 256, 0, stream>>>(slots, gsl, besl, cWq, qpad);
    attn_part<<<dim3(P_, B_), 256, 0, stream>>>(kbuf, vT, qpad, numpart, denpart);
    float* sout = (it == ITERS_ - 1) ? (float*)d_out : slots;
    gru_mlp<<<B_ * NS_, 512, 0, stream>>>(numpart, denpart, slots,
        cWih, cWhh, bih, bhh, cW1, b1, cW2, b2, gff, beff, sout);
  }
}